// Round 1
// baseline (1560.739 us; speedup 1.0000x reference)
//
#include <hip/hip_runtime.h>

#define DIM 256
#define NLAYER 4
#define BM 64
#define BN 64
#define BK 16

// ---------------- precompute kernels ----------------

__global__ void zero_int_kernel(int* __restrict__ p, int n) {
    int i = blockIdx.x * blockDim.x + threadIdx.x;
    if (i < n) p[i] = 0;
}

__global__ void deg_kernel(const int* __restrict__ dst, int E, int* __restrict__ deg) {
    int e = blockIdx.x * blockDim.x + threadIdx.x;
    if (e < E) atomicAdd(&deg[dst[e]], 1);
}

// single-block scan: row_off[0]=0; row_off[i+1] = sum_{j<=i} deg[j]
__global__ void scan_kernel(const int* __restrict__ deg, int N, int* __restrict__ row_off) {
    __shared__ int sdata[1024];
    int tid = threadIdx.x;
    int carry = 0;
    if (tid == 0) row_off[0] = 0;
    for (int base = 0; base < N; base += 1024) {
        int i = base + tid;
        int v = (i < N) ? deg[i] : 0;
        sdata[tid] = v;
        __syncthreads();
        for (int off = 1; off < 1024; off <<= 1) {
            int t = (tid >= off) ? sdata[tid - off] : 0;
            __syncthreads();
            sdata[tid] += t;
            __syncthreads();
        }
        if (i < N) row_off[i + 1] = sdata[tid] + carry;
        carry += sdata[1023];
        __syncthreads();
    }
}

__global__ void dinv_kernel(int* __restrict__ deg, float* __restrict__ dinv, int N) {
    int i = blockIdx.x * blockDim.x + threadIdx.x;
    if (i < N) {
        dinv[i] = rsqrtf((float)(deg[i] + 1));  // +1 self-loop
        deg[i] = 0;                              // reuse as cursor for fill
    }
}

__global__ void fill_kernel(const int* __restrict__ src, const int* __restrict__ dst, int E,
                            const int* __restrict__ row_off, int* __restrict__ cursor,
                            const float* __restrict__ dinv,
                            int* __restrict__ csr_src, float* __restrict__ csr_w) {
    int e = blockIdx.x * blockDim.x + threadIdx.x;
    if (e < E) {
        int d = dst[e], s = src[e];
        int pos = atomicAdd(&cursor[d], 1);
        int idx = row_off[d] + pos;
        csr_src[idx] = s;
        csr_w[idx] = dinv[s] * dinv[d];
    }
}

__global__ void copy_kernel(const float4* __restrict__ in, float4* __restrict__ out, int n4) {
    int i = blockIdx.x * blockDim.x + threadIdx.x;
    int stride = gridDim.x * blockDim.x;
    for (; i < n4; i += stride) out[i] = in[i];
}

// ---------------- per-layer kernels ----------------

// C[M x 256] = A[M x 256] @ B[256 x 256], fp32, row-major everywhere.
__global__ __launch_bounds__(256, 2) void gemm_kernel(const float* __restrict__ A,
                                                      const float* __restrict__ B,
                                                      float* __restrict__ C, int M) {
    __shared__ float As[BK][BM + 4];  // +4 pad: bank-spread, keeps float4 alignment
    __shared__ float Bs[BK][BN];
    int bx = blockIdx.x & 3;   // N tile 0..3
    int by = blockIdx.x >> 2;  // M tile
    int tid = threadIdx.x;
    int tx = tid & 15;   // output col group
    int ty = tid >> 4;   // output row group

    int a_row = tid >> 4;  // 0..15
    int a_col = tid & 15;  // k within K-tile
    int b_col = tid & 63;
    int b_row = tid >> 6;  // 0..3

    float acc[4][4] = {};

    for (int k0 = 0; k0 < DIM; k0 += BK) {
#pragma unroll
        for (int r = 0; r < 4; ++r) {
            int row = by * BM + a_row + 16 * r;
            float v = (row < M) ? A[(size_t)row * DIM + k0 + a_col] : 0.f;
            As[a_col][a_row + 16 * r] = v;
        }
#pragma unroll
        for (int r = 0; r < 4; ++r) {
            int krow = b_row + 4 * r;
            Bs[krow][b_col] = B[(size_t)(k0 + krow) * DIM + bx * BN + b_col];
        }
        __syncthreads();
#pragma unroll
        for (int k = 0; k < BK; ++k) {
            const float4 a4 = *(const float4*)&As[k][ty * 4];
            const float4 b4 = *(const float4*)&Bs[k][tx * 4];
            float av[4] = {a4.x, a4.y, a4.z, a4.w};
            float bv[4] = {b4.x, b4.y, b4.z, b4.w};
#pragma unroll
            for (int i = 0; i < 4; ++i)
#pragma unroll
                for (int j = 0; j < 4; ++j) acc[i][j] += av[i] * bv[j];
        }
        __syncthreads();
    }

#pragma unroll
    for (int i = 0; i < 4; ++i) {
        int row = by * BM + ty * 4 + i;
        if (row < M) {
            float4 v = make_float4(acc[i][0], acc[i][1], acc[i][2], acc[i][3]);
            *(float4*)&C[(size_t)row * DIM + bx * BN + tx * 4] = v;
        }
    }
}

// one wave per node; lane owns cols [lane*4, lane*4+4)
__global__ __launch_bounds__(256) void agg_kernel(const float* __restrict__ tmp,
                                                  const int* __restrict__ row_off,
                                                  const int* __restrict__ csr_src,
                                                  const float* __restrict__ csr_w,
                                                  const float* __restrict__ dinv,
                                                  const float* __restrict__ bias,
                                                  float* __restrict__ out, int N, int do_relu) {
    int node = blockIdx.x * 4 + (threadIdx.x >> 6);
    if (node >= N) return;
    int lane = threadIdx.x & 63;

    float4 acc = *(const float4*)&bias[lane * 4];
    float di = dinv[node];
    float w0 = di * di;  // self-loop weight
    float4 t = *(const float4*)&tmp[(size_t)node * DIM + lane * 4];
    acc.x += w0 * t.x; acc.y += w0 * t.y; acc.z += w0 * t.z; acc.w += w0 * t.w;

    int beg = row_off[node], end = row_off[node + 1];
    for (int e = beg; e < end; ++e) {
        int s = csr_src[e];
        float w = csr_w[e];
        float4 v = *(const float4*)&tmp[(size_t)s * DIM + lane * 4];
        acc.x += w * v.x; acc.y += w * v.y; acc.z += w * v.z; acc.w += w * v.w;
    }
    if (do_relu) {
        acc.x = fmaxf(acc.x, 0.f); acc.y = fmaxf(acc.y, 0.f);
        acc.z = fmaxf(acc.z, 0.f); acc.w = fmaxf(acc.w, 0.f);
    }
    *(float4*)&out[(size_t)node * DIM + lane * 4] = acc;
}

// ---------------- launch ----------------

extern "C" void kernel_launch(void* const* d_in, const int* in_sizes, int n_in,
                              void* d_out, int out_size, void* d_ws, size_t ws_size,
                              hipStream_t stream) {
    const float* x = (const float*)d_in[0];
    const int* edge = (const int*)d_in[1];
    const float* W = (const float*)d_in[2];
    const float* b = (const float*)d_in[3];
    float* out = (float*)d_out;

    const int N = in_sizes[0] / DIM;  // 50000
    const int E = in_sizes[1] / 2;    // 1600000
    const int* src = edge;
    const int* dst = edge + E;

    char* ws = (char*)d_ws;
    size_t off = 0;
    auto alloc = [&](size_t bytes) {
        void* p = ws + off;
        off += (bytes + 255) & ~(size_t)255;
        return p;
    };
    int* deg = (int*)alloc((size_t)N * 4);          // also reused as fill cursor
    int* row_off = (int*)alloc((size_t)(N + 1) * 4);
    float* dinv = (float*)alloc((size_t)N * 4);
    int* csr_src = (int*)alloc((size_t)E * 4);
    float* csr_w = (float*)alloc((size_t)E * 4);
    float* tmp = (float*)alloc((size_t)N * DIM * 4);
    (void)ws_size;

    // ---- graph precompute (once per launch; deterministic up to fp add order) ----
    zero_int_kernel<<<(N + 255) / 256, 256, 0, stream>>>(deg, N);
    deg_kernel<<<(E + 255) / 256, 256, 0, stream>>>(dst, E, deg);
    scan_kernel<<<1, 1024, 0, stream>>>(deg, N, row_off);
    dinv_kernel<<<(N + 255) / 256, 256, 0, stream>>>(deg, dinv, N);
    fill_kernel<<<(E + 255) / 256, 256, 0, stream>>>(src, dst, E, row_off, deg, dinv,
                                                     csr_src, csr_w);

    // out[0] = x
    copy_kernel<<<2048, 256, 0, stream>>>((const float4*)x, (float4*)out, N * DIM / 4);

    int gemm_grid = ((N + BM - 1) / BM) * (DIM / BN);
    for (int l = 0; l < NLAYER; ++l) {
        const float* h_in = (l == 0) ? x : out + (size_t)l * N * DIM;
        gemm_kernel<<<gemm_grid, 256, 0, stream>>>(h_in, W + (size_t)l * DIM * DIM, tmp, N);
        agg_kernel<<<(N + 3) / 4, 256, 0, stream>>>(tmp, row_off, csr_src, csr_w, dinv,
                                                    b + (size_t)l * DIM,
                                                    out + (size_t)(l + 1) * N * DIM, N,
                                                    (l < NLAYER - 1) ? 1 : 0);
    }
}

// Round 2
// 807.643 us; speedup vs baseline: 1.9325x; 1.9325x over previous
//
#include <hip/hip_runtime.h>

#define DIM 256
#define NLAYER 4

typedef __bf16 bf16x8 __attribute__((ext_vector_type(8)));
typedef float f32x4 __attribute__((ext_vector_type(4)));

__device__ __forceinline__ unsigned short f2bf(float f) {
    unsigned int u = __float_as_uint(f);
    u += 0x7fffu + ((u >> 16) & 1u);  // RTNE
    return (unsigned short)(u >> 16);
}
__device__ __forceinline__ float b2f(unsigned short u) {
    return __uint_as_float((unsigned int)u << 16);
}

#define GLL(g, l)                                                              \
    __builtin_amdgcn_global_load_lds(                                          \
        (const __attribute__((address_space(1))) void*)(g),                    \
        (__attribute__((address_space(3))) void*)(l), 16, 0, 0)

// ---------------- precompute kernels ----------------

__global__ void zero_int_kernel(int* __restrict__ p, int n) {
    int i = blockIdx.x * blockDim.x + threadIdx.x;
    if (i < n) p[i] = 0;
}

__global__ void deg_kernel(const int* __restrict__ dst, int E, int* __restrict__ deg) {
    int e = blockIdx.x * blockDim.x + threadIdx.x;
    if (e < E) atomicAdd(&deg[dst[e]], 1);
}

// single block; each thread owns a contiguous chunk, then log-scan of 1024 partials
__global__ void scan_kernel(const int* __restrict__ deg, int N, int* __restrict__ row_off) {
    __shared__ int part[1024];
    int tid = threadIdx.x;
    int CH = (N + 1023) >> 10;
    int beg = tid * CH;
    int end = beg + CH < N ? beg + CH : N;
    int s = 0;
    for (int i = beg; i < end; ++i) s += deg[i];
    part[tid] = s;
    __syncthreads();
    for (int off = 1; off < 1024; off <<= 1) {
        int t = (tid >= off) ? part[tid - off] : 0;
        __syncthreads();
        part[tid] += t;
        __syncthreads();
    }
    int run = (tid > 0) ? part[tid - 1] : 0;  // exclusive prefix
    for (int i = beg; i < end; ++i) {
        row_off[i] = run;
        run += deg[i];
    }
    if (tid == 1023) row_off[N] = part[1023];
}

__global__ void dinv_kernel(int* __restrict__ deg, float* __restrict__ dinv, int N) {
    int i = blockIdx.x * blockDim.x + threadIdx.x;
    if (i < N) {
        dinv[i] = rsqrtf((float)(deg[i] + 1));  // +1 self-loop
        deg[i] = 0;                              // reuse as fill cursor
    }
}

__global__ void fill_kernel(const int* __restrict__ src, const int* __restrict__ dst, int E,
                            const int* __restrict__ row_off, int* __restrict__ cursor,
                            const float* __restrict__ dinv,
                            int* __restrict__ csr_src, float* __restrict__ csr_w) {
    int e = blockIdx.x * blockDim.x + threadIdx.x;
    if (e < E) {
        int d = dst[e], s = src[e];
        int pos = atomicAdd(&cursor[d], 1);
        int idx = row_off[d] + pos;
        csr_src[idx] = s;
        csr_w[idx] = dinv[s] * dinv[d];
    }
}

// out[0] = x (fp32) and hb = bf16(x)
__global__ void copy_cvt_kernel(const float4* __restrict__ x, float4* __restrict__ out,
                                ushort4* __restrict__ hb, int n4) {
    int i = blockIdx.x * blockDim.x + threadIdx.x;
    int stride = gridDim.x * blockDim.x;
    for (; i < n4; i += stride) {
        float4 v = x[i];
        out[i] = v;
        ushort4 u;
        u.x = f2bf(v.x); u.y = f2bf(v.y); u.z = f2bf(v.z); u.w = f2bf(v.w);
        hb[i] = u;
    }
}

// Wt[l][c][k] = bf16(W[l][k][c])   (262144 elements total)
__global__ void wt_kernel(const float* __restrict__ W, unsigned short* __restrict__ Wt) {
    int i = blockIdx.x * 256 + threadIdx.x;
    int l = i >> 16, rem = i & 65535, c = rem >> 8, k = rem & 255;
    Wt[i] = f2bf(W[(l << 16) + k * 256 + c]);
}

// ---------------- bf16 MFMA GEMM: C[M x 256] = A[M x 256] @ W ----------------
// A bf16 row-major, Bt = W^T bf16 (Bt[col][k]), C bf16 row-major.
// Block: 256 thr (4 waves), tile 64 rows x 256 cols, BK=32, 8 K-steps.
__global__ __launch_bounds__(256, 2) void gemm_bf16(const unsigned short* __restrict__ A,
                                                    const unsigned short* __restrict__ Bt,
                                                    unsigned short* __restrict__ C, int M) {
    // LDS 32KB: As bytes [0,4096) = 64r x 32k, Bs bytes [4096,20480) = 256c x 32k,
    // epilogue reuses all 32KB as Cs[64][256] bf16. 16B units XOR-swizzled.
    __shared__ unsigned short lds[16384];
    const int tid = threadIdx.x;
    const int lane = tid & 63;
    const int w = tid >> 6;
    const int brow = blockIdx.x * 64;

    f32x4 acc[4][4] = {};

    // A staging: thread t -> LDS byte t*16 ; r=t>>2, stored-unit su=t&3,
    // logical unit u = su ^ ((r>>1)&3)  (inverse pre-swizzle on global src)
    const int ar = tid >> 2;
    const int au = (tid & 3) ^ ((ar >> 1) & 3);
    int agrow = brow + ar;
    if (agrow > M - 1) agrow = M - 1;
    const unsigned short* Ag = A + (size_t)agrow * 256 + au * 8;

    for (int k0 = 0; k0 < 256; k0 += 32) {
        GLL(Ag + k0, (char*)lds + tid * 16);
#pragma unroll
        for (int q = 0; q < 4; ++q) {
            int c = q * 64 + (tid >> 2);
            int u = (tid & 3) ^ ((c >> 1) & 3);
            GLL(Bt + (size_t)c * 256 + k0 + u * 8,
                (char*)lds + 4096 + (q * 256 + tid) * 16);
        }
        __syncthreads();  // drains vmcnt before barrier

        bf16x8 af[4], bfr[4];
#pragma unroll
        for (int mf = 0; mf < 4; ++mf) {
            int r = mf * 16 + (lane & 15);
            int su = (lane >> 4) ^ ((r >> 1) & 3);
            af[mf] = *(bf16x8*)((char*)lds + r * 64 + su * 16);
        }
#pragma unroll
        for (int nf = 0; nf < 4; ++nf) {
            int c = w * 64 + nf * 16 + (lane & 15);
            int su = (lane >> 4) ^ ((c >> 1) & 3);
            bfr[nf] = *(bf16x8*)((char*)lds + 4096 + c * 64 + su * 16);
        }
#pragma unroll
        for (int mf = 0; mf < 4; ++mf)
#pragma unroll
            for (int nf = 0; nf < 4; ++nf)
                acc[mf][nf] = __builtin_amdgcn_mfma_f32_16x16x32_bf16(af[mf], bfr[nf],
                                                                      acc[mf][nf], 0, 0, 0);
        __syncthreads();
    }

    // epilogue: acc -> Cs (bf16) -> coalesced global stores
#pragma unroll
    for (int mf = 0; mf < 4; ++mf)
#pragma unroll
        for (int nf = 0; nf < 4; ++nf)
#pragma unroll
            for (int j = 0; j < 4; ++j) {
                int r = mf * 16 + (lane >> 4) * 4 + j;  // C/D: row=(lane>>4)*4+reg
                int c = w * 64 + nf * 16 + (lane & 15); // col=lane&15
                lds[r * 256 + c] = f2bf(acc[mf][nf][j]);
            }
    __syncthreads();
#pragma unroll
    for (int q = 0; q < 8; ++q) {
        int s = q * 256 + tid;  // 16B unit
        int r = s >> 5;
        int off = s & 31;
        int grow = brow + r;
        if (grow < M)
            *(float4*)((char*)C + (size_t)grow * 512 + off * 16) =
                *(const float4*)((const char*)lds + s * 16);
    }
}

// ---------------- aggregation: one wave per node, bf16 gathers ----------------
__global__ __launch_bounds__(256) void agg_kernel(const unsigned short* __restrict__ tmp,
                                                  const int* __restrict__ row_off,
                                                  const int* __restrict__ csr_src,
                                                  const float* __restrict__ csr_w,
                                                  const float* __restrict__ dinv,
                                                  const float* __restrict__ bias,
                                                  float* __restrict__ out,
                                                  unsigned short* __restrict__ hnext,
                                                  int N, int do_relu) {
    int node = blockIdx.x * 4 + (threadIdx.x >> 6);
    if (node >= N) return;
    int lane = threadIdx.x & 63;
    const unsigned short* trow;

    float4 acc = *(const float4*)&bias[lane * 4];
    float di = dinv[node];
    float ws = di * di;  // self-loop weight
    trow = tmp + (size_t)node * DIM + lane * 4;
    {
        ushort4 v = *(const ushort4*)trow;
        acc.x += ws * b2f(v.x); acc.y += ws * b2f(v.y);
        acc.z += ws * b2f(v.z); acc.w += ws * b2f(v.w);
    }

    int e = row_off[node], end = row_off[node + 1];
    for (; e + 4 <= end; e += 4) {
        int s0 = csr_src[e], s1 = csr_src[e + 1], s2 = csr_src[e + 2], s3 = csr_src[e + 3];
        float w0 = csr_w[e], w1 = csr_w[e + 1], w2 = csr_w[e + 2], w3 = csr_w[e + 3];
        ushort4 v0 = *(const ushort4*)&tmp[(size_t)s0 * DIM + lane * 4];
        ushort4 v1 = *(const ushort4*)&tmp[(size_t)s1 * DIM + lane * 4];
        ushort4 v2 = *(const ushort4*)&tmp[(size_t)s2 * DIM + lane * 4];
        ushort4 v3 = *(const ushort4*)&tmp[(size_t)s3 * DIM + lane * 4];
        acc.x += w0 * b2f(v0.x) + w1 * b2f(v1.x) + w2 * b2f(v2.x) + w3 * b2f(v3.x);
        acc.y += w0 * b2f(v0.y) + w1 * b2f(v1.y) + w2 * b2f(v2.y) + w3 * b2f(v3.y);
        acc.z += w0 * b2f(v0.z) + w1 * b2f(v1.z) + w2 * b2f(v2.z) + w3 * b2f(v3.z);
        acc.w += w0 * b2f(v0.w) + w1 * b2f(v1.w) + w2 * b2f(v2.w) + w3 * b2f(v3.w);
    }
    for (; e < end; ++e) {
        int s = csr_src[e];
        float wgt = csr_w[e];
        ushort4 v = *(const ushort4*)&tmp[(size_t)s * DIM + lane * 4];
        acc.x += wgt * b2f(v.x); acc.y += wgt * b2f(v.y);
        acc.z += wgt * b2f(v.z); acc.w += wgt * b2f(v.w);
    }
    if (do_relu) {
        acc.x = fmaxf(acc.x, 0.f); acc.y = fmaxf(acc.y, 0.f);
        acc.z = fmaxf(acc.z, 0.f); acc.w = fmaxf(acc.w, 0.f);
    }
    *(float4*)&out[(size_t)node * DIM + lane * 4] = acc;
    if (hnext) {
        ushort4 u;
        u.x = f2bf(acc.x); u.y = f2bf(acc.y); u.z = f2bf(acc.z); u.w = f2bf(acc.w);
        *(ushort4*)&hnext[(size_t)node * DIM + lane * 4] = u;
    }
}

// ---------------- launch ----------------

extern "C" void kernel_launch(void* const* d_in, const int* in_sizes, int n_in,
                              void* d_out, int out_size, void* d_ws, size_t ws_size,
                              hipStream_t stream) {
    const float* x = (const float*)d_in[0];
    const int* edge = (const int*)d_in[1];
    const float* W = (const float*)d_in[2];
    const float* b = (const float*)d_in[3];
    float* out = (float*)d_out;

    const int N = in_sizes[0] / DIM;  // 50000
    const int E = in_sizes[1] / 2;    // 1600000
    const int* src = edge;
    const int* dst = edge + E;

    char* ws = (char*)d_ws;
    size_t off = 0;
    auto alloc = [&](size_t bytes) {
        void* p = ws + off;
        off += (bytes + 255) & ~(size_t)255;
        return p;
    };
    int* deg = (int*)alloc((size_t)N * 4);  // reused as fill cursor
    int* row_off = (int*)alloc((size_t)(N + 1) * 4);
    float* dinv = (float*)alloc((size_t)N * 4);
    int* csr_src = (int*)alloc((size_t)E * 4);
    float* csr_w = (float*)alloc((size_t)E * 4);
    unsigned short* tmp_b = (unsigned short*)alloc((size_t)N * DIM * 2);
    unsigned short* hb = (unsigned short*)alloc((size_t)N * DIM * 2);
    unsigned short* Wt = (unsigned short*)alloc((size_t)NLAYER * DIM * DIM * 2);
    (void)ws_size;

    // graph precompute (deterministic up to fp add order)
    zero_int_kernel<<<(N + 255) / 256, 256, 0, stream>>>(deg, N);
    deg_kernel<<<(E + 255) / 256, 256, 0, stream>>>(dst, E, deg);
    scan_kernel<<<1, 1024, 0, stream>>>(deg, N, row_off);
    dinv_kernel<<<(N + 255) / 256, 256, 0, stream>>>(deg, dinv, N);
    fill_kernel<<<(E + 255) / 256, 256, 0, stream>>>(src, dst, E, row_off, deg, dinv,
                                                     csr_src, csr_w);
    wt_kernel<<<NLAYER * DIM * DIM / 256, 256, 0, stream>>>(W, Wt);

    // out[0] = x ; hb = bf16(x)
    copy_cvt_kernel<<<2048, 256, 0, stream>>>((const float4*)x, (float4*)out,
                                              (ushort4*)hb, N * DIM / 4);

    int gemm_grid = (N + 63) / 64;
    for (int l = 0; l < NLAYER; ++l) {
        gemm_bf16<<<gemm_grid, 256, 0, stream>>>(hb, Wt + (size_t)l * DIM * DIM, tmp_b, N);
        agg_kernel<<<(N + 3) / 4, 256, 0, stream>>>(
            tmp_b, row_off, csr_src, csr_w, dinv, b + (size_t)l * DIM,
            out + (size_t)(l + 1) * N * DIM,
            (l < NLAYER - 1) ? hb : (unsigned short*)nullptr, N,
            (l < NLAYER - 1) ? 1 : 0);
    }
}

// Round 3
// 582.590 us; speedup vs baseline: 2.6790x; 1.3863x over previous
//
#include <hip/hip_runtime.h>

#define DIM 256
#define NLAYER 4

typedef __bf16 bf16x8 __attribute__((ext_vector_type(8)));
typedef float f32x4 __attribute__((ext_vector_type(4)));
typedef float f32x2 __attribute__((ext_vector_type(2)));

__device__ __forceinline__ unsigned short f2bf(float f) {
    unsigned int u = __float_as_uint(f);
    u += 0x7fffu + ((u >> 16) & 1u);  // RTNE
    return (unsigned short)(u >> 16);
}
__device__ __forceinline__ float b2f(unsigned short u) {
    return __uint_as_float((unsigned int)u << 16);
}

#define GLL(g, l)                                                              \
    __builtin_amdgcn_global_load_lds(                                          \
        (const __attribute__((address_space(1))) void*)(g),                    \
        (__attribute__((address_space(3))) void*)(l), 16, 0, 0)

// ---------------- precompute kernels ----------------

__global__ void zero_int_kernel(int* __restrict__ p, int n) {
    int i = blockIdx.x * blockDim.x + threadIdx.x;
    if (i < n) p[i] = 0;
}

__global__ void deg_kernel(const int* __restrict__ dst, int E, int* __restrict__ deg) {
    int e = blockIdx.x * blockDim.x + threadIdx.x;
    if (e < E) atomicAdd(&deg[dst[e]], 1);
}

// single block; each thread owns a contiguous chunk, then log-scan of 1024 partials
__global__ void scan_kernel(const int* __restrict__ deg, int N, int* __restrict__ row_off) {
    __shared__ int part[1024];
    int tid = threadIdx.x;
    int CH = (N + 1023) >> 10;
    int beg = tid * CH;
    int end = beg + CH < N ? beg + CH : N;
    int s = 0;
    for (int i = beg; i < end; ++i) s += deg[i];
    part[tid] = s;
    __syncthreads();
    for (int off = 1; off < 1024; off <<= 1) {
        int t = (tid >= off) ? part[tid - off] : 0;
        __syncthreads();
        part[tid] += t;
        __syncthreads();
    }
    int run = (tid > 0) ? part[tid - 1] : 0;  // exclusive prefix
    for (int i = beg; i < end; ++i) {
        row_off[i] = run;
        run += deg[i];
    }
    if (tid == 1023) row_off[N] = part[1023];
}

__global__ void dinv_kernel(int* __restrict__ deg, float* __restrict__ dinv, int N) {
    int i = blockIdx.x * blockDim.x + threadIdx.x;
    if (i < N) {
        dinv[i] = rsqrtf((float)(deg[i] + 1));  // +1 self-loop
        deg[i] = 0;                              // reuse as fill cursor
    }
}

__global__ void fill_kernel(const int* __restrict__ src, const int* __restrict__ dst, int E,
                            const int* __restrict__ row_off, int* __restrict__ cursor,
                            const float* __restrict__ dinv,
                            int2* __restrict__ csr) {
    int e = blockIdx.x * blockDim.x + threadIdx.x;
    if (e < E) {
        int d = dst[e], s = src[e];
        int pos = atomicAdd(&cursor[d], 1);
        int idx = row_off[d] + pos;
        csr[idx] = make_int2(s, __float_as_int(dinv[s] * dinv[d]));
    }
}

// out[0] = x (fp32) and hb = bf16(x)
__global__ void copy_cvt_kernel(const float4* __restrict__ x, float4* __restrict__ out,
                                ushort4* __restrict__ hb, int n4) {
    int i = blockIdx.x * blockDim.x + threadIdx.x;
    int stride = gridDim.x * blockDim.x;
    for (; i < n4; i += stride) {
        float4 v = x[i];
        out[i] = v;
        ushort4 u;
        u.x = f2bf(v.x); u.y = f2bf(v.y); u.z = f2bf(v.z); u.w = f2bf(v.w);
        hb[i] = u;
    }
}

// Wt[l][c][k] = bf16(W[l][k][c])
__global__ void wt_kernel(const float* __restrict__ W, unsigned short* __restrict__ Wt) {
    int i = blockIdx.x * 256 + threadIdx.x;
    int l = i >> 16, rem = i & 65535, c = rem >> 8, k = rem & 255;
    Wt[i] = f2bf(W[(l << 16) + k * 256 + c]);
}

// ---------------- bf16 MFMA GEMM: C(fp8) [M x 256] = A(bf16) @ W ----------------
// A bf16 row-major, Bt = W^T bf16 (Bt[col][k]), C fp8 e4m3 row-major.
__global__ __launch_bounds__(256, 2) void gemm_bf16(const unsigned short* __restrict__ A,
                                                    const unsigned short* __restrict__ Bt,
                                                    unsigned char* __restrict__ C, int M) {
    // LDS 32KB: As bytes [0,4096) = 64r x 32k, Bs bytes [4096,20480) = 256c x 32k,
    // epilogue reuses first 16KB as Cs[64][256] fp8. 16B units XOR-swizzled.
    __shared__ unsigned short lds[16384];
    const int tid = threadIdx.x;
    const int lane = tid & 63;
    const int w = tid >> 6;
    const int brow = blockIdx.x * 64;

    f32x4 acc[4][4] = {};

    const int ar = tid >> 2;
    const int au = (tid & 3) ^ ((ar >> 1) & 3);
    int agrow = brow + ar;
    if (agrow > M - 1) agrow = M - 1;
    const unsigned short* Ag = A + (size_t)agrow * 256 + au * 8;

    for (int k0 = 0; k0 < 256; k0 += 32) {
        GLL(Ag + k0, (char*)lds + tid * 16);
#pragma unroll
        for (int q = 0; q < 4; ++q) {
            int c = q * 64 + (tid >> 2);
            int u = (tid & 3) ^ ((c >> 1) & 3);
            GLL(Bt + (size_t)c * 256 + k0 + u * 8,
                (char*)lds + 4096 + (q * 256 + tid) * 16);
        }
        __syncthreads();  // drains vmcnt before barrier

        bf16x8 af[4], bfr[4];
#pragma unroll
        for (int mf = 0; mf < 4; ++mf) {
            int r = mf * 16 + (lane & 15);
            int su = (lane >> 4) ^ ((r >> 1) & 3);
            af[mf] = *(bf16x8*)((char*)lds + r * 64 + su * 16);
        }
#pragma unroll
        for (int nf = 0; nf < 4; ++nf) {
            int c = w * 64 + nf * 16 + (lane & 15);
            int su = (lane >> 4) ^ ((c >> 1) & 3);
            bfr[nf] = *(bf16x8*)((char*)lds + 4096 + c * 64 + su * 16);
        }
#pragma unroll
        for (int mf = 0; mf < 4; ++mf)
#pragma unroll
            for (int nf = 0; nf < 4; ++nf)
                acc[mf][nf] = __builtin_amdgcn_mfma_f32_16x16x32_bf16(af[mf], bfr[nf],
                                                                      acc[mf][nf], 0, 0, 0);
        __syncthreads();
    }

    // epilogue: acc -> Cs (fp8 e4m3, RNE) -> coalesced global stores
    unsigned char* cs = (unsigned char*)lds;
#pragma unroll
    for (int mf = 0; mf < 4; ++mf)
#pragma unroll
        for (int nf = 0; nf < 4; ++nf)
#pragma unroll
            for (int j = 0; j < 4; ++j) {
                int r = mf * 16 + (lane >> 4) * 4 + j;  // C/D: row=(lane>>4)*4+reg
                int c = w * 64 + nf * 16 + (lane & 15); // col=lane&15
                int pk = __builtin_amdgcn_cvt_pk_fp8_f32(acc[mf][nf][j], acc[mf][nf][j],
                                                         0, false);
                cs[r * 256 + c] = (unsigned char)pk;
            }
    __syncthreads();
#pragma unroll
    for (int q = 0; q < 4; ++q) {
        int s = q * 256 + tid;  // 16B unit of Cs (64 rows x 256B)
        int r = s >> 4;
        int o = s & 15;
        int grow = brow + r;
        if (grow < M)
            *(float4*)&C[(size_t)grow * 256 + o * 16] = *(const float4*)&cs[s * 16];
    }
}

// ---------------- aggregation: one wave per node, fp8 gathers ----------------

__device__ __forceinline__ void accum_fp8(float4& acc, unsigned int v, float w) {
    f32x2 lo = __builtin_amdgcn_cvt_pk_f32_fp8((int)v, false);
    f32x2 hi = __builtin_amdgcn_cvt_pk_f32_fp8((int)v, true);
    acc.x += w * lo[0]; acc.y += w * lo[1];
    acc.z += w * hi[0]; acc.w += w * hi[1];
}

__global__ __launch_bounds__(256) void agg_kernel(const unsigned char* __restrict__ tmp,
                                                  const int* __restrict__ row_off,
                                                  const int2* __restrict__ csr,
                                                  const float* __restrict__ dinv,
                                                  const float* __restrict__ bias,
                                                  float* __restrict__ out,
                                                  unsigned short* __restrict__ hnext,
                                                  int N, int do_relu) {
    int node = blockIdx.x * 4 + (threadIdx.x >> 6);
    if (node >= N) return;
    int lane = threadIdx.x & 63;

    float4 acc = make_float4(bias[lane * 4], bias[lane * 4 + 1],
                             bias[lane * 4 + 2], bias[lane * 4 + 3]);
    float di = dinv[node];
    {  // self-loop message
        unsigned int v = *(const unsigned int*)&tmp[(size_t)node * 256 + lane * 4];
        accum_fp8(acc, v, di * di);
    }

    int e = row_off[node], end = row_off[node + 1];
    for (; e + 8 <= end; e += 8) {
        int2 sw[8];
        unsigned int v[8];
#pragma unroll
        for (int i = 0; i < 8; ++i) sw[i] = csr[e + i];
#pragma unroll
        for (int i = 0; i < 8; ++i)
            v[i] = *(const unsigned int*)&tmp[(size_t)(unsigned)sw[i].x * 256 + lane * 4];
#pragma unroll
        for (int i = 0; i < 8; ++i) accum_fp8(acc, v[i], __int_as_float(sw[i].y));
    }
    for (; e < end; ++e) {
        int2 sw = csr[e];
        unsigned int v = *(const unsigned int*)&tmp[(size_t)(unsigned)sw.x * 256 + lane * 4];
        accum_fp8(acc, v, __int_as_float(sw.y));
    }

    if (do_relu) {
        acc.x = fmaxf(acc.x, 0.f); acc.y = fmaxf(acc.y, 0.f);
        acc.z = fmaxf(acc.z, 0.f); acc.w = fmaxf(acc.w, 0.f);
    }
    *(float4*)&out[(size_t)node * DIM + lane * 4] = acc;
    if (hnext) {
        ushort4 u;
        u.x = f2bf(acc.x); u.y = f2bf(acc.y); u.z = f2bf(acc.z); u.w = f2bf(acc.w);
        *(ushort4*)&hnext[(size_t)node * DIM + lane * 4] = u;
    }
}

// ---------------- launch ----------------

extern "C" void kernel_launch(void* const* d_in, const int* in_sizes, int n_in,
                              void* d_out, int out_size, void* d_ws, size_t ws_size,
                              hipStream_t stream) {
    const float* x = (const float*)d_in[0];
    const int* edge = (const int*)d_in[1];
    const float* W = (const float*)d_in[2];
    const float* b = (const float*)d_in[3];
    float* out = (float*)d_out;

    const int N = in_sizes[0] / DIM;  // 50000
    const int E = in_sizes[1] / 2;    // 1600000
    const int* src = edge;
    const int* dst = edge + E;

    char* ws = (char*)d_ws;
    size_t off = 0;
    auto alloc = [&](size_t bytes) {
        void* p = ws + off;
        off += (bytes + 255) & ~(size_t)255;
        return p;
    };
    int* deg = (int*)alloc((size_t)N * 4);  // reused as fill cursor
    int* row_off = (int*)alloc((size_t)(N + 1) * 4);
    float* dinv = (float*)alloc((size_t)N * 4);
    int2* csr = (int2*)alloc((size_t)E * 8);
    unsigned char* tmp8 = (unsigned char*)alloc((size_t)N * DIM);  // fp8 messages
    unsigned short* hb = (unsigned short*)alloc((size_t)N * DIM * 2);
    unsigned short* Wt = (unsigned short*)alloc((size_t)NLAYER * DIM * DIM * 2);
    (void)ws_size;

    // graph precompute (deterministic up to fp add order)
    zero_int_kernel<<<(N + 255) / 256, 256, 0, stream>>>(deg, N);
    deg_kernel<<<(E + 255) / 256, 256, 0, stream>>>(dst, E, deg);
    scan_kernel<<<1, 1024, 0, stream>>>(deg, N, row_off);
    dinv_kernel<<<(N + 255) / 256, 256, 0, stream>>>(deg, dinv, N);
    fill_kernel<<<(E + 255) / 256, 256, 0, stream>>>(src, dst, E, row_off, deg, dinv, csr);
    wt_kernel<<<NLAYER * DIM * DIM / 256, 256, 0, stream>>>(W, Wt);

    // out[0] = x ; hb = bf16(x)
    copy_cvt_kernel<<<2048, 256, 0, stream>>>((const float4*)x, (float4*)out,
                                              (ushort4*)hb, N * DIM / 4);

    int gemm_grid = (N + 63) / 64;
    for (int l = 0; l < NLAYER; ++l) {
        gemm_bf16<<<gemm_grid, 256, 0, stream>>>(hb, Wt + (size_t)l * DIM * DIM, tmp8, N);
        agg_kernel<<<(N + 3) / 4, 256, 0, stream>>>(
            tmp8, row_off, csr, dinv, b + (size_t)l * DIM,
            out + (size_t)(l + 1) * N * DIM,
            (l < NLAYER - 1) ? hb : (unsigned short*)nullptr, N,
            (l < NLAYER - 1) ? 1 : 0);
    }
}

// Round 4
// 527.027 us; speedup vs baseline: 2.9614x; 1.1054x over previous
//
#include <hip/hip_runtime.h>

#define DIM 256
#define NLAYER 4

typedef __bf16 bf16x8 __attribute__((ext_vector_type(8)));
typedef float f32x4 __attribute__((ext_vector_type(4)));
typedef float f32x2 __attribute__((ext_vector_type(2)));
typedef int i32x2 __attribute__((ext_vector_type(2)));

__device__ __forceinline__ unsigned short f2bf(float f) {
    unsigned int u = __float_as_uint(f);
    u += 0x7fffu + ((u >> 16) & 1u);  // RTNE
    return (unsigned short)(u >> 16);
}

#define GLL(g, l)                                                              \
    __builtin_amdgcn_global_load_lds(                                          \
        (const __attribute__((address_space(1))) void*)(g),                    \
        (__attribute__((address_space(3))) void*)(l), 16, 0, 0)

// ---------------- precompute kernels ----------------

__global__ void zero_int_kernel(int* __restrict__ p, int n) {
    int i = blockIdx.x * blockDim.x + threadIdx.x;
    if (i < n) p[i] = 0;
}

__global__ void deg_kernel(const int* __restrict__ dst, int E, int* __restrict__ deg) {
    int e = blockIdx.x * blockDim.x + threadIdx.x;
    if (e < E) atomicAdd(&deg[dst[e]], 1);
}

// phase A: per-block (256 elems) sums of deg
__global__ void scanA_kernel(const int* __restrict__ deg, int N, int* __restrict__ bsum) {
    int i = blockIdx.x * 256 + threadIdx.x;
    int v = (i < N) ? deg[i] : 0;
#pragma unroll
    for (int o = 1; o < 64; o <<= 1) v += __shfl_xor(v, o);
    __shared__ int ws[4];
    if ((threadIdx.x & 63) == 0) ws[threadIdx.x >> 6] = v;
    __syncthreads();
    if (threadIdx.x == 0) bsum[blockIdx.x] = ws[0] + ws[1] + ws[2] + ws[3];
}

// phase B: single block, exclusive scan of nb block sums (nb <= 1024)
__global__ void scanB_kernel(int* __restrict__ bsum, int nb) {
    __shared__ int s[1024];
    int tid = threadIdx.x;
    int v = (tid < nb) ? bsum[tid] : 0;
    s[tid] = v;
    __syncthreads();
    for (int o = 1; o < 1024; o <<= 1) {
        int t = (tid >= o) ? s[tid - o] : 0;
        __syncthreads();
        s[tid] += t;
        __syncthreads();
    }
    if (tid < nb) bsum[tid] = s[tid] - v;  // exclusive
}

// phase C: row_off[i], dinv[i], zero cursor (deg reused)
__global__ void scanC_kernel(int* __restrict__ deg, int N, const int* __restrict__ boff,
                             int* __restrict__ row_off, float* __restrict__ dinv) {
    __shared__ int s[256];
    int tid = threadIdx.x;
    int i = blockIdx.x * 256 + tid;
    int v = (i < N) ? deg[i] : 0;
    s[tid] = v;
    __syncthreads();
    for (int o = 1; o < 256; o <<= 1) {
        int t = (tid >= o) ? s[tid - o] : 0;
        __syncthreads();
        s[tid] += t;
        __syncthreads();
    }
    int excl = s[tid] - v + boff[blockIdx.x];
    if (i < N) {
        row_off[i] = excl;
        dinv[i] = rsqrtf((float)(v + 1));  // +1 self-loop
        deg[i] = 0;                         // cursor for fill
    }
    if (i == N - 1) row_off[N] = excl + v;
}

__global__ void fill_kernel(const int* __restrict__ src, const int* __restrict__ dst, int E,
                            const int* __restrict__ row_off, int* __restrict__ cursor,
                            const float* __restrict__ dinv,
                            i32x2* __restrict__ csr) {
    int e = blockIdx.x * blockDim.x + threadIdx.x;
    if (e < E) {
        int d = dst[e], s = src[e];
        int pos = atomicAdd(&cursor[d], 1);
        i32x2 ent;
        ent.x = s;
        ent.y = __float_as_int(dinv[s] * dinv[d]);
        csr[row_off[d] + pos] = ent;
    }
}

// out[0] = x (fp32, NT) and hb = bf16(x)
__global__ void copy_cvt_kernel(const f32x4* __restrict__ x, f32x4* __restrict__ out,
                                ushort4* __restrict__ hb, int n4) {
    int i = blockIdx.x * blockDim.x + threadIdx.x;
    int stride = gridDim.x * blockDim.x;
    for (; i < n4; i += stride) {
        f32x4 v = x[i];
        __builtin_nontemporal_store(v, &out[i]);
        ushort4 u;
        u.x = f2bf(v[0]); u.y = f2bf(v[1]); u.z = f2bf(v[2]); u.w = f2bf(v[3]);
        hb[i] = u;
    }
}

// Wt[l][c][k] = bf16(W[l][k][c])
__global__ void wt_kernel(const float* __restrict__ W, unsigned short* __restrict__ Wt) {
    int i = blockIdx.x * 256 + threadIdx.x;
    int l = i >> 16, rem = i & 65535, c = rem >> 8, k = rem & 255;
    Wt[i] = f2bf(W[(l << 16) + k * 256 + c]);
}

// ------- bf16 MFMA GEMM: C(fp8)[M x 256] = A(bf16) @ W ; 128x256 tile -------
// A bf16 row-major, Bt = W^T bf16 (Bt[col][k]), C fp8 e4m3 row-major.
// 256 thr (4 waves); each wave owns 64-col strip x 128 rows. BK=32, 8 K-steps.
__global__ __launch_bounds__(256, 2) void gemm_bf16(const unsigned short* __restrict__ A,
                                                    const unsigned short* __restrict__ Bt,
                                                    unsigned char* __restrict__ C, int M) {
    // LDS 32KB: As bytes [0,8192) = 128r x 32k; Bs [8192,24576) = 256c x 32k;
    // epilogue reuses all 32KB as Cs[128][256] fp8. 16B units XOR-swizzled.
    __shared__ unsigned short lds[16384];
    const int tid = threadIdx.x;
    const int lane = tid & 63;
    const int w = tid >> 6;
    const int brow = blockIdx.x * 128;

    f32x4 acc[8][4] = {};

    // A staging: stored-unit u -> row r=u>>2, slot su=u&3, logical lu=su^((r>>1)&3)
    const int ar0 = tid >> 2;
    const int alu = (tid & 3) ^ ((ar0 >> 1) & 3);
    int agrow0 = brow + ar0;       if (agrow0 > M - 1) agrow0 = M - 1;
    int agrow1 = brow + ar0 + 64;  if (agrow1 > M - 1) agrow1 = M - 1;
    const unsigned short* Ag0 = A + (size_t)agrow0 * 256 + alu * 8;
    const unsigned short* Ag1 = A + (size_t)agrow1 * 256 + alu * 8;
    // B staging: col for q-th GLL: c=q*64+(tid>>2); lu same for all q
    const int blu = (tid & 3) ^ (((tid >> 2) >> 1) & 3);
    const unsigned short* Bg = Bt + (size_t)(tid >> 2) * 256 + blu * 8;

    for (int k0 = 0; k0 < 256; k0 += 32) {
        GLL(Ag0 + k0, (char*)lds + tid * 16);
        GLL(Ag1 + k0, (char*)lds + 4096 + tid * 16);
#pragma unroll
        for (int q = 0; q < 4; ++q)
            GLL(Bg + (size_t)q * 64 * 256 + k0,
                (char*)lds + 8192 + (q * 256 + tid) * 16);
        __syncthreads();  // drains vmcnt before barrier

        bf16x8 af[8], bfr[4];
#pragma unroll
        for (int mf = 0; mf < 8; ++mf) {
            int r = mf * 16 + (lane & 15);
            int su = (lane >> 4) ^ ((r >> 1) & 3);
            af[mf] = *(bf16x8*)((char*)lds + r * 64 + su * 16);
        }
#pragma unroll
        for (int nf = 0; nf < 4; ++nf) {
            int c = w * 64 + nf * 16 + (lane & 15);
            int su = (lane >> 4) ^ ((c >> 1) & 3);
            bfr[nf] = *(bf16x8*)((char*)lds + 8192 + c * 64 + su * 16);
        }
#pragma unroll
        for (int mf = 0; mf < 8; ++mf)
#pragma unroll
            for (int nf = 0; nf < 4; ++nf)
                acc[mf][nf] = __builtin_amdgcn_mfma_f32_16x16x32_bf16(af[mf], bfr[nf],
                                                                      acc[mf][nf], 0, 0, 0);
        __syncthreads();
    }

    // epilogue: acc -> Cs (fp8 e4m3, RNE) -> coalesced global stores
    unsigned char* cs = (unsigned char*)lds;
#pragma unroll
    for (int mf = 0; mf < 8; ++mf)
#pragma unroll
        for (int nf = 0; nf < 4; ++nf)
#pragma unroll
            for (int j = 0; j < 4; ++j) {
                int r = mf * 16 + (lane >> 4) * 4 + j;  // C/D: row=(lane>>4)*4+reg
                int c = w * 64 + nf * 16 + (lane & 15); // col=lane&15
                int pk = __builtin_amdgcn_cvt_pk_fp8_f32(acc[mf][nf][j], acc[mf][nf][j],
                                                         0, false);
                cs[r * 256 + c] = (unsigned char)pk;
            }
    __syncthreads();
#pragma unroll
    for (int q = 0; q < 8; ++q) {
        int s = q * 256 + tid;  // 16B unit of Cs (128 rows x 256B)
        int r = s >> 4;
        int o = s & 15;
        int grow = brow + r;
        if (grow < M)
            *(f32x4*)&C[(size_t)grow * 256 + o * 16] = *(const f32x4*)&cs[s * 16];
    }
}

// ---------------- aggregation: one wave per node, fp8 gathers ----------------

__device__ __forceinline__ void accum_fp8(float4& acc, unsigned int v, float w) {
    f32x2 lo = __builtin_amdgcn_cvt_pk_f32_fp8((int)v, false);
    f32x2 hi = __builtin_amdgcn_cvt_pk_f32_fp8((int)v, true);
    acc.x += w * lo[0]; acc.y += w * lo[1];
    acc.z += w * hi[0]; acc.w += w * hi[1];
}

__global__ __launch_bounds__(256) void agg_kernel(const unsigned char* __restrict__ tmp,
                                                  const int* __restrict__ row_off,
                                                  const i32x2* __restrict__ csr,
                                                  const float* __restrict__ dinv,
                                                  const float* __restrict__ bias,
                                                  float* __restrict__ out,
                                                  unsigned short* __restrict__ hnext,
                                                  int N, int do_relu) {
    int node = blockIdx.x * 4 + (threadIdx.x >> 6);
    if (node >= N) return;
    int lane = threadIdx.x & 63;

    float4 acc;
    {
        f32x4 b4 = *(const f32x4*)&bias[lane * 4];
        acc = make_float4(b4[0], b4[1], b4[2], b4[3]);
    }
    float di = dinv[node];
    {  // self-loop message
        unsigned int v = *(const unsigned int*)&tmp[(size_t)node * 256 + lane * 4];
        accum_fp8(acc, v, di * di);
    }

    int e = row_off[node], end = row_off[node + 1];
    for (; e + 16 <= end; e += 16) {
        i32x2 sw[16];
        unsigned int v[16];
#pragma unroll
        for (int i = 0; i < 16; ++i) sw[i] = __builtin_nontemporal_load(&csr[e + i]);
#pragma unroll
        for (int i = 0; i < 16; ++i)
            v[i] = *(const unsigned int*)&tmp[(size_t)(unsigned)sw[i].x * 256 + lane * 4];
#pragma unroll
        for (int i = 0; i < 16; ++i) accum_fp8(acc, v[i], __int_as_float(sw[i].y));
    }
    for (; e + 4 <= end; e += 4) {
        i32x2 sw[4];
        unsigned int v[4];
#pragma unroll
        for (int i = 0; i < 4; ++i) sw[i] = __builtin_nontemporal_load(&csr[e + i]);
#pragma unroll
        for (int i = 0; i < 4; ++i)
            v[i] = *(const unsigned int*)&tmp[(size_t)(unsigned)sw[i].x * 256 + lane * 4];
#pragma unroll
        for (int i = 0; i < 4; ++i) accum_fp8(acc, v[i], __int_as_float(sw[i].y));
    }
    for (; e < end; ++e) {
        i32x2 sw = __builtin_nontemporal_load(&csr[e]);
        unsigned int v = *(const unsigned int*)&tmp[(size_t)(unsigned)sw.x * 256 + lane * 4];
        accum_fp8(acc, v, __int_as_float(sw.y));
    }

    if (do_relu) {
        acc.x = fmaxf(acc.x, 0.f); acc.y = fmaxf(acc.y, 0.f);
        acc.z = fmaxf(acc.z, 0.f); acc.w = fmaxf(acc.w, 0.f);
    }
    f32x4 ov; ov[0] = acc.x; ov[1] = acc.y; ov[2] = acc.z; ov[3] = acc.w;
    __builtin_nontemporal_store(ov, (f32x4*)&out[(size_t)node * DIM + lane * 4]);
    if (hnext) {
        ushort4 u;
        u.x = f2bf(acc.x); u.y = f2bf(acc.y); u.z = f2bf(acc.z); u.w = f2bf(acc.w);
        *(ushort4*)&hnext[(size_t)node * DIM + lane * 4] = u;
    }
}

// ---------------- launch ----------------

extern "C" void kernel_launch(void* const* d_in, const int* in_sizes, int n_in,
                              void* d_out, int out_size, void* d_ws, size_t ws_size,
                              hipStream_t stream) {
    const float* x = (const float*)d_in[0];
    const int* edge = (const int*)d_in[1];
    const float* W = (const float*)d_in[2];
    const float* b = (const float*)d_in[3];
    float* out = (float*)d_out;

    const int N = in_sizes[0] / DIM;  // 50000
    const int E = in_sizes[1] / 2;    // 1600000
    const int* src = edge;
    const int* dst = edge + E;
    const int NB = (N + 255) / 256;   // 196 scan blocks

    char* ws = (char*)d_ws;
    size_t off = 0;
    auto alloc = [&](size_t bytes) {
        void* p = ws + off;
        off += (bytes + 255) & ~(size_t)255;
        return p;
    };
    int* deg = (int*)alloc((size_t)N * 4);  // reused as fill cursor
    int* row_off = (int*)alloc((size_t)(N + 1) * 4);
    int* bsum = (int*)alloc((size_t)NB * 4);
    float* dinv = (float*)alloc((size_t)N * 4);
    i32x2* csr = (i32x2*)alloc((size_t)E * 8);
    unsigned char* tmp8 = (unsigned char*)alloc((size_t)N * DIM);  // fp8 messages
    unsigned short* hb = (unsigned short*)alloc((size_t)N * DIM * 2);
    unsigned short* Wt = (unsigned short*)alloc((size_t)NLAYER * DIM * DIM * 2);
    (void)ws_size;

    // graph precompute (deterministic up to fp add order)
    zero_int_kernel<<<NB, 256, 0, stream>>>(deg, N);
    deg_kernel<<<(E + 255) / 256, 256, 0, stream>>>(dst, E, deg);
    scanA_kernel<<<NB, 256, 0, stream>>>(deg, N, bsum);
    scanB_kernel<<<1, 1024, 0, stream>>>(bsum, NB);
    scanC_kernel<<<NB, 256, 0, stream>>>(deg, N, bsum, row_off, dinv);
    fill_kernel<<<(E + 255) / 256, 256, 0, stream>>>(src, dst, E, row_off, deg, dinv, csr);
    wt_kernel<<<NLAYER * DIM * DIM / 256, 256, 0, stream>>>(W, Wt);

    // out[0] = x ; hb = bf16(x)
    copy_cvt_kernel<<<2048, 256, 0, stream>>>((const f32x4*)x, (f32x4*)out,
                                              (ushort4*)hb, N * DIM / 4);

    int gemm_grid = (N + 127) / 128;
    for (int l = 0; l < NLAYER; ++l) {
        gemm_bf16<<<gemm_grid, 256, 0, stream>>>(hb, Wt + (size_t)l * DIM * DIM, tmp8, N);
        agg_kernel<<<(N + 3) / 4, 256, 0, stream>>>(
            tmp8, row_off, csr, dinv, b + (size_t)l * DIM,
            out + (size_t)(l + 1) * N * DIM,
            (l < NLAYER - 1) ? hb : (unsigned short*)nullptr, N,
            (l < NLAYER - 1) ? 1 : 0);
    }
}